// Round 1
// baseline (1283.475 us; speedup 1.0000x reference)
//
#include <hip/hip_runtime.h>
#include <math.h>

#define THREADS 256
#define WAVES (THREADS / 64)

// One block per row. Fused single pass:
//   - sum of exp(logit)          (unstabilized, faithful to reference)
//   - top-2 (value, index)       (strict >, ties measure-zero for random fp32)
// Epilogue: first = (argmax == y) ? top2_val : top1_val
//           out   = first - log(S - first)     // subtract the LOGIT, per reference
__global__ __launch_bounds__(THREADS) void Fitness_29918742183959_kernel(
    const float* __restrict__ logits,
    const int*   __restrict__ y,
    float*       __restrict__ out,
    int C)
{
    const int row = blockIdx.x;
    const int tid = threadIdx.x;
    const float4* rowp =
        reinterpret_cast<const float4*>(logits + (size_t)row * (size_t)C);
    const int n4 = C >> 2;

    // 4 independent accumulators for ILP (and slightly better summation error)
    float s0 = 0.f, s1 = 0.f, s2 = 0.f, s3 = 0.f;
    float v1 = -INFINITY, v2 = -INFINITY;  // top-1 / top-2 values
    int   i1 = -1,        i2 = -1;         // their column indices

    for (int i = tid; i < n4; i += THREADS) {
        float4 v = rowp[i];      // coalesced: lane t reads float4 #t of the chunk
        const int base = i << 2;
        s0 += __expf(v.x);
        s1 += __expf(v.y);
        s2 += __expf(v.z);
        s3 += __expf(v.w);
        if (v.x > v2) { if (v.x > v1) { v2 = v1; i2 = i1; v1 = v.x; i1 = base;     } else { v2 = v.x; i2 = base;     } }
        if (v.y > v2) { if (v.y > v1) { v2 = v1; i2 = i1; v1 = v.y; i1 = base + 1; } else { v2 = v.y; i2 = base + 1; } }
        if (v.z > v2) { if (v.z > v1) { v2 = v1; i2 = i1; v1 = v.z; i1 = base + 2; } else { v2 = v.z; i2 = base + 2; } }
        if (v.w > v2) { if (v.w > v1) { v2 = v1; i2 = i1; v1 = v.w; i1 = base + 3; } else { v2 = v.w; i2 = base + 3; } }
    }
    float s = (s0 + s1) + (s2 + s3);

    // ---- wave (64-lane) reduction: sum + top-2 merge ----
    #pragma unroll
    for (int off = 32; off > 0; off >>= 1) {
        s += __shfl_down(s, off, 64);
        float ov1 = __shfl_down(v1, off, 64);
        int   oi1 = __shfl_down(i1, off, 64);
        float ov2 = __shfl_down(v2, off, 64);
        int   oi2 = __shfl_down(i2, off, 64);
        if (ov1 > v1) {
            // other's best wins; new runner-up = max(our best, other's runner-up)
            float c2 = v1; int c2i = i1;
            if (ov2 > c2) { c2 = ov2; c2i = oi2; }
            v1 = ov1; i1 = oi1; v2 = c2; i2 = c2i;
        } else if (ov1 > v2) {
            v2 = ov1; i2 = oi1;
        }
    }

    // ---- cross-wave reduction via LDS (4 waves) ----
    __shared__ float sh_s[WAVES], sh_v1[WAVES], sh_v2[WAVES];
    __shared__ int   sh_i1[WAVES], sh_i2[WAVES];
    const int wave = tid >> 6;
    const int lane = tid & 63;
    if (lane == 0) {
        sh_s[wave] = s; sh_v1[wave] = v1; sh_i1[wave] = i1;
        sh_v2[wave] = v2; sh_i2[wave] = i2;
    }
    __syncthreads();
    if (tid == 0) {
        for (int w = 1; w < WAVES; ++w) {
            s += sh_s[w];
            float ov1 = sh_v1[w], ov2 = sh_v2[w];
            int   oi1 = sh_i1[w], oi2 = sh_i2[w];
            if (ov1 > v1) {
                float c2 = v1; int c2i = i1;
                if (ov2 > c2) { c2 = ov2; c2i = oi2; }
                v1 = ov1; i1 = oi1; v2 = c2; i2 = c2i;
            } else if (ov1 > v2) {
                v2 = ov1; i2 = oi1;
            }
        }
        const int label = y[row];
        const float first = (i1 == label) ? v2 : v1;
        out[row] = first - logf(s - first);
    }
}

extern "C" void kernel_launch(void* const* d_in, const int* in_sizes, int n_in,
                              void* d_out, int out_size, void* d_ws, size_t ws_size,
                              hipStream_t stream) {
    const float* logits = (const float*)d_in[0];
    const int*   y      = (const int*)d_in[1];
    float*       out    = (float*)d_out;
    const int B = in_sizes[1];                 // 2048
    const int C = in_sizes[0] / B;             // 128000
    Fitness_29918742183959_kernel<<<B, THREADS, 0, stream>>>(logits, y, out, C);
}

// Round 2
// 1232.952 us; speedup vs baseline: 1.0410x; 1.0410x over previous
//
#include <hip/hip_runtime.h>
#include <math.h>

#define THREADS 256
#define WAVES (THREADS / 64)

// native clang vector so __builtin_nontemporal_load accepts it
typedef float vf4 __attribute__((ext_vector_type(4)));

// One block per row (2048 blocks, 8/CU, 32 waves/CU).
// Single fused pass per row:
//   S = sum(exp(logit))                      (unstabilized, faithful to reference)
//   M = max over j != label of logit[j]      (== "first" in the reference:
//        if argmax==label it's the runner-up, else it's the argmax)
// out = M - log(S - M)                       (subtract the LOGIT, per reference)
__global__ __launch_bounds__(THREADS) void Fitness_29918742183959_kernel(
    const float* __restrict__ logits,
    const int*   __restrict__ y,
    float*       __restrict__ out,
    int C)
{
    const int row = blockIdx.x;
    const int tid = threadIdx.x;
    const int n4 = C >> 2;
    const vf4* __restrict__ rowp =
        reinterpret_cast<const vf4*>(logits + (size_t)row * (size_t)C);
    const int label = y[row];      // wave-uniform scalar load
    const int lq = label >> 2;     // float4 slot holding the label
    const int lk = label & 3;      // component within that slot

    // 8 sum accumulators + 4 max accumulators: short dependency chains, ILP
    float s0=0.f,s1=0.f,s2=0.f,s3=0.f,s4=0.f,s5=0.f,s6=0.f,s7=0.f;
    float m0=-INFINITY, m1=-INFINITY, m2=-INFINITY, m3=-INFINITY;

    int i = tid;
    // unrolled x2: two independent float4 loads in flight per thread
    for (; i + THREADS < n4; i += 2 * THREADS) {
        vf4 a = __builtin_nontemporal_load(&rowp[i]);
        vf4 b = __builtin_nontemporal_load(&rowp[i + THREADS]);
        s0 += __expf(a.x); s1 += __expf(a.y); s2 += __expf(a.z); s3 += __expf(a.w);
        s4 += __expf(b.x); s5 += __expf(b.y); s6 += __expf(b.z); s7 += __expf(b.w);
        // mask the label element out of the max path (sum already consumed it).
        // Taken by at most one thread in one iteration per block -> execz skip.
        if (__builtin_expect(i == lq, 0)) {
            if (lk == 0) a.x = -INFINITY; else if (lk == 1) a.y = -INFINITY;
            else if (lk == 2) a.z = -INFINITY; else a.w = -INFINITY;
        }
        if (__builtin_expect(i + THREADS == lq, 0)) {
            if (lk == 0) b.x = -INFINITY; else if (lk == 1) b.y = -INFINITY;
            else if (lk == 2) b.z = -INFINITY; else b.w = -INFINITY;
        }
        m0 = fmaxf(m0, fmaxf(a.x, b.x));
        m1 = fmaxf(m1, fmaxf(a.y, b.y));
        m2 = fmaxf(m2, fmaxf(a.z, b.z));
        m3 = fmaxf(m3, fmaxf(a.w, b.w));
    }
    if (i < n4) {  // tail (125 iters/thread = 62 pairs + 1)
        vf4 a = __builtin_nontemporal_load(&rowp[i]);
        s0 += __expf(a.x); s1 += __expf(a.y); s2 += __expf(a.z); s3 += __expf(a.w);
        if (i == lq) {
            if (lk == 0) a.x = -INFINITY; else if (lk == 1) a.y = -INFINITY;
            else if (lk == 2) a.z = -INFINITY; else a.w = -INFINITY;
        }
        m0 = fmaxf(m0, a.x); m1 = fmaxf(m1, a.y);
        m2 = fmaxf(m2, a.z); m3 = fmaxf(m3, a.w);
    }
    float s = ((s0 + s1) + (s2 + s3)) + ((s4 + s5) + (s6 + s7));
    float m = fmaxf(fmaxf(m0, m1), fmaxf(m2, m3));

    // ---- 64-lane wave reduction ----
    #pragma unroll
    for (int off = 32; off; off >>= 1) {
        s += __shfl_down(s, off, 64);
        m = fmaxf(m, __shfl_down(m, off, 64));
    }

    // ---- cross-wave reduction ----
    __shared__ float sh_s[WAVES], sh_m[WAVES];
    const int wave = tid >> 6, lane = tid & 63;
    if (lane == 0) { sh_s[wave] = s; sh_m[wave] = m; }
    __syncthreads();
    if (tid == 0) {
        for (int w = 1; w < WAVES; ++w) { s += sh_s[w]; m = fmaxf(m, sh_m[w]); }
        out[row] = m - logf(s - m);
    }
}

extern "C" void kernel_launch(void* const* d_in, const int* in_sizes, int n_in,
                              void* d_out, int out_size, void* d_ws, size_t ws_size,
                              hipStream_t stream) {
    const float* logits = (const float*)d_in[0];
    const int*   y      = (const int*)d_in[1];
    float*       out    = (float*)d_out;
    const int B = in_sizes[1];                 // 2048
    const int C = in_sizes[0] / B;             // 128000
    Fitness_29918742183959_kernel<<<B, THREADS, 0, stream>>>(logits, y, out, C);
}